// Round 4
// baseline (170.157 us; speedup 1.0000x reference)
//
#include <hip/hip_runtime.h>
#include <hip/hip_bf16.h>
#include <math.h>

#define NB 8
#define SQ 2048
#define NSP 8    // kv splits in flash pass

typedef __attribute__((ext_vector_type(8))) short short8;
typedef __attribute__((ext_vector_type(4))) float f32x4;

__device__ __forceinline__ short f2bf(float f) {
    union { float f; unsigned u; } v; v.f = f;
    unsigned r = v.u + 0x7FFF + ((v.u >> 16) & 1);  // RNE
    return (short)(r >> 16);
}

// ---------------- K0: build WT bf16 [192][256]  (rows 0-63 Wq, 64-127 Wk, 128-191 Wv)
__global__ __launch_bounds__(256) void k_wt(const float* __restrict__ Wq,
                                            const float* __restrict__ Wk,
                                            const float* __restrict__ Wv,
                                            short* __restrict__ wt) {
    int o = blockIdx.x * 256 + threadIdx.x;   // < 192*256
    int row = o >> 8, e = o & 255;
    int w = row >> 6, d = row & 63;
    const float* W = (w == 0) ? Wq : ((w == 1) ? Wk : Wv);
    wt[o] = f2bf(W[e * 64 + d]);
}

// ---------------- K1: projection GEMM, 16 rows/block, waves split cols {q,k,v}
__global__ __launch_bounds__(256, 4) void k_proj(const float* __restrict__ obs,
                                                 const short* __restrict__ wt,
                                                 short* __restrict__ qw,
                                                 short* __restrict__ kw,
                                                 short* __restrict__ vt) {
    int tid = threadIdx.x, w = tid >> 6, l = tid & 63, lg = l >> 4, lc = l & 15;
    int r0 = blockIdx.x * 16;
    int arow = r0 + lc;
    f32x4 accq = {0.f,0.f,0.f,0.f}, acck = {0.f,0.f,0.f,0.f}, accv = {0.f,0.f,0.f,0.f};
    const short* wq = wt + (size_t)(w * 16 + lc) * 256;
    const short* wk = wt + (size_t)(64 + w * 16 + lc) * 256;
    const short* wv = wt + (size_t)(128 + w * 16 + lc) * 256;
    #pragma unroll
    for (int ks = 0; ks < 8; ++ks) {
        int e0 = ks * 32 + lg * 8;
        const float* ap = obs + (size_t)arow * 256 + e0;
        float4 f0 = *(const float4*)ap;
        float4 f1 = *(const float4*)(ap + 4);
        short8 a;
        a[0] = f2bf(f0.x); a[1] = f2bf(f0.y); a[2] = f2bf(f0.z); a[3] = f2bf(f0.w);
        a[4] = f2bf(f1.x); a[5] = f2bf(f1.y); a[6] = f2bf(f1.z); a[7] = f2bf(f1.w);
        accq = __builtin_amdgcn_mfma_f32_16x16x32_bf16(a, *(const short8*)(wq + e0), accq, 0, 0, 0);
        acck = __builtin_amdgcn_mfma_f32_16x16x32_bf16(a, *(const short8*)(wk + e0), acck, 0, 0, 0);
        accv = __builtin_amdgcn_mfma_f32_16x16x32_bf16(a, *(const short8*)(wv + e0), accv, 0, 0, 0);
    }
    const float scale = 0.35355339059327373f;  // 64^-0.25
    __shared__ short ldsv[64][18];
    #pragma unroll
    for (int r = 0; r < 4; ++r) {
        int row = r0 + lg * 4 + r;
        qw[(size_t)row * 64 + w * 16 + lc] = f2bf(accq[r] * scale);
        kw[(size_t)row * 64 + w * 16 + lc] = f2bf(acck[r] * scale);
        ldsv[w * 16 + lc][lg * 4 + r] = f2bf(accv[r]);
    }
    __syncthreads();
    int b = r0 >> 11, s0 = r0 & 2047;
    int d = tid >> 2, sc = (tid & 3) * 4;
    short* dst = vt + (size_t)b * 64 * SQ + (size_t)d * SQ + s0 + sc;
    dst[0] = ldsv[d][sc]; dst[1] = ldsv[d][sc + 1];
    dst[2] = ldsv[d][sc + 2]; dst[3] = ldsv[d][sc + 3];
}

// ---------------- K2: flash partials — block (qb, sp, b): kv tiles sp, sp+8, ... <= qb
__global__ __launch_bounds__(256) void k_flash(const short* __restrict__ qw,
                                               const short* __restrict__ kw,
                                               const short* __restrict__ vt,
                                               float* __restrict__ op,
                                               float* __restrict__ mlpart) {
    int qb = blockIdx.x, sp = blockIdx.y, b = blockIdx.z;
    if (sp > qb) return;
    int q0 = qb * 64;
    int tid = threadIdx.x, w = tid >> 6, l = tid & 63, lg = l >> 4, lc = l & 15;
    int r0 = q0 + w * 16;
    int eo = lg * 8;
    __shared__ short ldsP[4][16][72];
    const short* qbase = qw + (size_t)b * SQ * 64;
    const short* kbase = kw + (size_t)b * SQ * 64;
    const short* vbase = vt + (size_t)b * 64 * SQ;
    short8 qf0 = *(const short8*)(qbase + (size_t)(r0 + lc) * 64 + eo);
    short8 qf1 = *(const short8*)(qbase + (size_t)(r0 + lc) * 64 + 32 + eo);
    float m[4], lsum[4];
    f32x4 o[4];
    #pragma unroll
    for (int r = 0; r < 4; ++r) { m[r] = -INFINITY; lsum[r] = 0.f; }
    #pragma unroll
    for (int nj = 0; nj < 4; ++nj) o[nj] = (f32x4){0.f, 0.f, 0.f, 0.f};

    for (int kb = sp; kb <= qb; kb += NSP) {
        int k0 = kb * 64;
        f32x4 s[4];
        #pragma unroll
        for (int nj = 0; nj < 4; ++nj) s[nj] = (f32x4){0.f, 0.f, 0.f, 0.f};
        #pragma unroll
        for (int nj = 0; nj < 4; ++nj) {
            short8 kf = *(const short8*)(kbase + (size_t)(k0 + nj * 16 + lc) * 64 + eo);
            s[nj] = __builtin_amdgcn_mfma_f32_16x16x32_bf16(qf0, kf, s[nj], 0, 0, 0);
        }
        #pragma unroll
        for (int nj = 0; nj < 4; ++nj) {
            short8 kf = *(const short8*)(kbase + (size_t)(k0 + nj * 16 + lc) * 64 + 32 + eo);
            s[nj] = __builtin_amdgcn_mfma_f32_16x16x32_bf16(qf1, kf, s[nj], 0, 0, 0);
        }
        if (kb == qb) {
            #pragma unroll
            for (int nj = 0; nj < 4; ++nj)
                #pragma unroll
                for (int r = 0; r < 4; ++r)
                    if (k0 + nj * 16 + lc > r0 + lg * 4 + r) s[nj][r] = -INFINITY;
        }
        #pragma unroll
        for (int r = 0; r < 4; ++r) {
            float pm = fmaxf(fmaxf(s[0][r], s[1][r]), fmaxf(s[2][r], s[3][r]));
            pm = fmaxf(pm, __shfl_xor(pm, 1));
            pm = fmaxf(pm, __shfl_xor(pm, 2));
            pm = fmaxf(pm, __shfl_xor(pm, 4));
            pm = fmaxf(pm, __shfl_xor(pm, 8));
            float mn = fmaxf(m[r], pm);
            float sc = __expf(m[r] - mn);   // first tile: exp(-inf)=0
            m[r] = mn;
            lsum[r] *= sc;
            #pragma unroll
            for (int nj = 0; nj < 4; ++nj) o[nj][r] *= sc;
            float ps = 0.f;
            #pragma unroll
            for (int nj = 0; nj < 4; ++nj) {
                float p = __expf(s[nj][r] - mn);
                ps += p;
                ldsP[w][lg * 4 + r][nj * 16 + lc] = f2bf(p);
            }
            ps += __shfl_xor(ps, 1);
            ps += __shfl_xor(ps, 2);
            ps += __shfl_xor(ps, 4);
            ps += __shfl_xor(ps, 8);
            lsum[r] += ps;
        }
        #pragma unroll
        for (int ks = 0; ks < 2; ++ks) {
            short8 pa = *(const short8*)&ldsP[w][lc][ks * 32 + lg * 8];
            #pragma unroll
            for (int nj = 0; nj < 4; ++nj) {
                short8 vf = *(const short8*)(vbase + (size_t)(nj * 16 + lc) * SQ + k0 + ks * 32 + eo);
                o[nj] = __builtin_amdgcn_mfma_f32_16x16x32_bf16(pa, vf, o[nj], 0, 0, 0);
            }
        }
    }
    size_t pb = ((size_t)sp * NB + b) * SQ;
    #pragma unroll
    for (int r = 0; r < 4; ++r) {
        int row = r0 + lg * 4 + r;
        if (lc == 0) {
            mlpart[(pb + row) * 2]     = m[r];
            mlpart[(pb + row) * 2 + 1] = lsum[r];
        }
        #pragma unroll
        for (int nj = 0; nj < 4; ++nj)
            op[(pb + row) * 64 + nj * 16 + lc] = o[nj][r];
    }
}

// ---------------- K3: combine partials -> ml_final + fused MLP -> x
__global__ __launch_bounds__(256) void k_combine(const float* __restrict__ op,
                                                 const float* __restrict__ mlpart,
                                                 const float* __restrict__ W1,
                                                 const float* __restrict__ b1,
                                                 const float* __restrict__ W2,
                                                 const float* __restrict__ b2,
                                                 float* __restrict__ x,
                                                 float* __restrict__ mlf) {
    int qb = blockIdx.x, b = blockIdx.y;
    int s0 = qb * 64;
    int nsp = (qb + 1 < NSP) ? (qb + 1) : NSP;
    int tid = threadIdx.x;
    __shared__ float wgt[NSP][64];
    __shared__ float linv_s[64];
    __shared__ float ao[64][68];
    if (tid < 64) {
        int row = s0 + tid;
        float mm[NSP], ll[NSP];
        float mf = -INFINITY;
        #pragma unroll
        for (int sp = 0; sp < NSP; ++sp) {
            if (sp < nsp) {
                mm[sp] = mlpart[(((size_t)sp * NB + b) * SQ + row) * 2];
                ll[sp] = mlpart[(((size_t)sp * NB + b) * SQ + row) * 2 + 1];
            } else { mm[sp] = -INFINITY; ll[sp] = 0.f; }
            mf = fmaxf(mf, mm[sp]);
        }
        float lf = 0.f;
        #pragma unroll
        for (int sp = 0; sp < NSP; ++sp) {
            float wv = __expf(mm[sp] - mf);   // -inf -> 0
            wgt[sp][tid] = wv;
            lf += wv * ll[sp];
        }
        float inv = 1.f / lf;
        linv_s[tid] = inv;
        mlf[((size_t)b * SQ + row) * 2]     = mf;
        mlf[((size_t)b * SQ + row) * 2 + 1] = inv;
    }
    __syncthreads();
    int row = tid >> 2, cg = (tid & 3) * 16;
    float acc[16];
    #pragma unroll
    for (int j = 0; j < 16; ++j) acc[j] = 0.f;
    for (int sp = 0; sp < NSP; ++sp) {
        if (sp >= nsp) break;
        const float* src = op + (((size_t)sp * NB + b) * SQ + s0 + row) * 64 + cg;
        float wv = wgt[sp][row];
        #pragma unroll
        for (int j = 0; j < 4; ++j) {
            float4 v = *(const float4*)(src + j * 4);
            acc[j*4+0] += wv * v.x; acc[j*4+1] += wv * v.y;
            acc[j*4+2] += wv * v.z; acc[j*4+3] += wv * v.w;
        }
    }
    float inv = linv_s[row];
    #pragma unroll
    for (int j = 0; j < 16; ++j) ao[row][cg + j] = acc[j] * inv;
    __syncthreads();
    int w = tid >> 6, l = tid & 63;
    for (int rr = 0; rr < 16; ++rr) {
        int rowloc = w * 16 + rr;
        float t = 0.f;
        #pragma unroll 8
        for (int d = 0; d < 64; ++d) t += ao[rowloc][d] * W1[d * 64 + l];
        float h = fmaxf(t + b1[l], 0.f);
        float px = h * W2[l];
        px += __shfl_xor(px, 1);
        px += __shfl_xor(px, 2);
        px += __shfl_xor(px, 4);
        px += __shfl_xor(px, 8);
        px += __shfl_xor(px, 16);
        px += __shfl_xor(px, 32);
        if (l == 0) x[(size_t)b * SQ + s0 + rowloc] = px + b2[0];
    }
}

// ---------------- K4: attn writer — recompute S, write exp(S-m)*invl; zeros above diag
__global__ __launch_bounds__(256) void k_attnw(const short* __restrict__ qw,
                                               const short* __restrict__ kw,
                                               const float* __restrict__ mlf,
                                               float* __restrict__ attn) {
    int kb = blockIdx.x, qb = blockIdx.y, b = blockIdx.z;
    int q0 = qb * 64, k0 = kb * 64;
    float* abase = attn + (size_t)b * SQ * SQ;
    int tid = threadIdx.x;
    if (kb > qb) {   // strictly-upper tile: pure zero-fill, fully coalesced
        int row = q0 + (tid >> 2);
        float4* dst = (float4*)(abase + (size_t)row * SQ + k0 + (tid & 3) * 16);
        float4 z = {0.f, 0.f, 0.f, 0.f};
        dst[0] = z; dst[1] = z; dst[2] = z; dst[3] = z;
        return;
    }
    int w = tid >> 6, l = tid & 63, lg = l >> 4, lc = l & 15;
    int r0 = q0 + w * 16, eo = lg * 8;
    const short* qbase = qw + (size_t)b * SQ * 64;
    const short* kbase = kw + (size_t)b * SQ * 64;
    short8 qf0 = *(const short8*)(qbase + (size_t)(r0 + lc) * 64 + eo);
    short8 qf1 = *(const short8*)(qbase + (size_t)(r0 + lc) * 64 + 32 + eo);
    f32x4 s[4];
    #pragma unroll
    for (int nj = 0; nj < 4; ++nj) s[nj] = (f32x4){0.f, 0.f, 0.f, 0.f};
    #pragma unroll
    for (int nj = 0; nj < 4; ++nj) {
        short8 kf = *(const short8*)(kbase + (size_t)(k0 + nj * 16 + lc) * 64 + eo);
        s[nj] = __builtin_amdgcn_mfma_f32_16x16x32_bf16(qf0, kf, s[nj], 0, 0, 0);
    }
    #pragma unroll
    for (int nj = 0; nj < 4; ++nj) {
        short8 kf = *(const short8*)(kbase + (size_t)(k0 + nj * 16 + lc) * 64 + 32 + eo);
        s[nj] = __builtin_amdgcn_mfma_f32_16x16x32_bf16(qf1, kf, s[nj], 0, 0, 0);
    }
    #pragma unroll
    for (int r = 0; r < 4; ++r) {
        int row = r0 + lg * 4 + r;
        float mr = mlf[((size_t)b * SQ + row) * 2];
        float iv = mlf[((size_t)b * SQ + row) * 2 + 1];
        #pragma unroll
        for (int nj = 0; nj < 4; ++nj) {
            int col = k0 + nj * 16 + lc;
            float p = (col <= row) ? __expf(s[nj][r] - mr) * iv : 0.f;
            abase[(size_t)row * SQ + col] = p;
        }
    }
}

extern "C" void kernel_launch(void* const* d_in, const int* in_sizes, int n_in,
                              void* d_out, int out_size, void* d_ws, size_t ws_size,
                              hipStream_t stream) {
    const float* obs = (const float*)d_in[0];
    const float* Wq  = (const float*)d_in[2];
    const float* Wk  = (const float*)d_in[3];
    const float* Wv  = (const float*)d_in[4];
    const float* W1  = (const float*)d_in[5];
    const float* b1  = (const float*)d_in[6];
    const float* W2  = (const float*)d_in[7];
    const float* b2  = (const float*)d_in[8];

    float* x    = (float*)d_out;                    // [16384]
    float* attn = (float*)d_out + NB * SQ;          // [8][2048][2048]

    // flash partials live inside the attn output region (fully overwritten by k_attnw)
    float* op     = attn;                                   // 8 sp * 16384 rows * 64 f32 = 32 MiB
    float* mlpart = attn + (size_t)NSP * NB * SQ * 64;      // 8 sp * 16384 * 2 f32 = 1 MiB

    char* ws = (char*)d_ws;
    short* wt  = (short*)(ws);                      // 192*256 bf16
    short* qw  = (short*)(ws + 131072);             // 16384*64 bf16
    short* kw  = (short*)(ws + 2228224);            // 16384*64 bf16
    short* vt  = (short*)(ws + 4325376);            // 8*64*2048 bf16
    float* mlf = (float*)(ws + 6422528);            // 16384*2 f32 (m, 1/l)

    k_wt<<<dim3(192), dim3(256), 0, stream>>>(Wq, Wk, Wv, wt);
    k_proj<<<dim3(1024), dim3(256), 0, stream>>>(obs, wt, qw, kw, vt);
    k_flash<<<dim3(32, NSP, NB), dim3(256), 0, stream>>>(qw, kw, vt, op, mlpart);
    k_combine<<<dim3(32, NB), dim3(256), 0, stream>>>(op, mlpart, W1, b1, W2, b2, x, mlf);
    k_attnw<<<dim3(32, 32, NB), dim3(256), 0, stream>>>(qw, kw, mlf, attn);
}

// Round 5
// 158.802 us; speedup vs baseline: 1.0715x; 1.0715x over previous
//
#include <hip/hip_runtime.h>
#include <hip/hip_bf16.h>
#include <math.h>

#define NB 8
#define SQ 2048
#define NSP 8    // kv splits in flash pass

typedef __attribute__((ext_vector_type(8))) short short8;
typedef __attribute__((ext_vector_type(4))) float f32x4;

__device__ __forceinline__ short f2bf(float f) {
    union { float f; unsigned u; } v; v.f = f;
    unsigned r = v.u + 0x7FFF + ((v.u >> 16) & 1);  // RNE
    return (short)(r >> 16);
}

// ---------------- K0: build WT bf16 [192][256]  (rows 0-63 Wq, 64-127 Wk, 128-191 Wv)
__global__ __launch_bounds__(256) void k_wt(const float* __restrict__ Wq,
                                            const float* __restrict__ Wk,
                                            const float* __restrict__ Wv,
                                            short* __restrict__ wt) {
    int o = blockIdx.x * 256 + threadIdx.x;   // < 192*256
    int row = o >> 8, e = o & 255;
    int w = row >> 6, d = row & 63;
    const float* W = (w == 0) ? Wq : ((w == 1) ? Wk : Wv);
    wt[o] = f2bf(W[e * 64 + d]);
}

// ---------------- K1: projection GEMM, 16 rows/block, waves split cols {q,k,v}
__global__ __launch_bounds__(256, 4) void k_proj(const float* __restrict__ obs,
                                                 const short* __restrict__ wt,
                                                 short* __restrict__ qw,
                                                 short* __restrict__ kw,
                                                 short* __restrict__ vt) {
    int tid = threadIdx.x, w = tid >> 6, l = tid & 63, lg = l >> 4, lc = l & 15;
    int r0 = blockIdx.x * 16;
    int arow = r0 + lc;
    f32x4 accq = {0.f,0.f,0.f,0.f}, acck = {0.f,0.f,0.f,0.f}, accv = {0.f,0.f,0.f,0.f};
    const short* wq = wt + (size_t)(w * 16 + lc) * 256;
    const short* wk = wt + (size_t)(64 + w * 16 + lc) * 256;
    const short* wv = wt + (size_t)(128 + w * 16 + lc) * 256;
    #pragma unroll
    for (int ks = 0; ks < 8; ++ks) {
        int e0 = ks * 32 + lg * 8;
        const float* ap = obs + (size_t)arow * 256 + e0;
        float4 f0 = *(const float4*)ap;
        float4 f1 = *(const float4*)(ap + 4);
        short8 a;
        a[0] = f2bf(f0.x); a[1] = f2bf(f0.y); a[2] = f2bf(f0.z); a[3] = f2bf(f0.w);
        a[4] = f2bf(f1.x); a[5] = f2bf(f1.y); a[6] = f2bf(f1.z); a[7] = f2bf(f1.w);
        accq = __builtin_amdgcn_mfma_f32_16x16x32_bf16(a, *(const short8*)(wq + e0), accq, 0, 0, 0);
        acck = __builtin_amdgcn_mfma_f32_16x16x32_bf16(a, *(const short8*)(wk + e0), acck, 0, 0, 0);
        accv = __builtin_amdgcn_mfma_f32_16x16x32_bf16(a, *(const short8*)(wv + e0), accv, 0, 0, 0);
    }
    const float scale = 0.35355339059327373f;  // 64^-0.25
    __shared__ short ldsv[64][18];
    #pragma unroll
    for (int r = 0; r < 4; ++r) {
        int row = r0 + lg * 4 + r;
        qw[(size_t)row * 64 + w * 16 + lc] = f2bf(accq[r] * scale);
        kw[(size_t)row * 64 + w * 16 + lc] = f2bf(acck[r] * scale);
        ldsv[w * 16 + lc][lg * 4 + r] = f2bf(accv[r]);
    }
    __syncthreads();
    int b = r0 >> 11, s0 = r0 & 2047;
    int d = tid >> 2, sc = (tid & 3) * 4;
    short* dst = vt + (size_t)b * 64 * SQ + (size_t)d * SQ + s0 + sc;
    dst[0] = ldsv[d][sc]; dst[1] = ldsv[d][sc + 1];
    dst[2] = ldsv[d][sc + 2]; dst[3] = ldsv[d][sc + 3];
}

// ---------------- K2: flash partials, NO max-shift — o = sum exp(s)*v, l = sum exp(s)
__global__ __launch_bounds__(256) void k_flash(const short* __restrict__ qw,
                                               const short* __restrict__ kw,
                                               const short* __restrict__ vt,
                                               float* __restrict__ op,
                                               float* __restrict__ lpart) {
    int qb = blockIdx.x, sp = blockIdx.y, b = blockIdx.z;
    if (sp > qb) return;
    int q0 = qb * 64;
    int tid = threadIdx.x, w = tid >> 6, l = tid & 63, lg = l >> 4, lc = l & 15;
    int r0 = q0 + w * 16;
    int eo = lg * 8;
    __shared__ short ldsP[4][16][72];
    const short* qbase = qw + (size_t)b * SQ * 64;
    const short* kbase = kw + (size_t)b * SQ * 64;
    const short* vbase = vt + (size_t)b * 64 * SQ;
    short8 qf0 = *(const short8*)(qbase + (size_t)(r0 + lc) * 64 + eo);
    short8 qf1 = *(const short8*)(qbase + (size_t)(r0 + lc) * 64 + 32 + eo);
    float lsum[4];
    f32x4 o[4];
    #pragma unroll
    for (int r = 0; r < 4; ++r) lsum[r] = 0.f;
    #pragma unroll
    for (int nj = 0; nj < 4; ++nj) o[nj] = (f32x4){0.f, 0.f, 0.f, 0.f};

    for (int kb = sp; kb <= qb; kb += NSP) {
        int k0 = kb * 64;
        f32x4 s[4];
        #pragma unroll
        for (int nj = 0; nj < 4; ++nj) s[nj] = (f32x4){0.f, 0.f, 0.f, 0.f};
        #pragma unroll
        for (int nj = 0; nj < 4; ++nj) {
            short8 kf = *(const short8*)(kbase + (size_t)(k0 + nj * 16 + lc) * 64 + eo);
            s[nj] = __builtin_amdgcn_mfma_f32_16x16x32_bf16(qf0, kf, s[nj], 0, 0, 0);
        }
        #pragma unroll
        for (int nj = 0; nj < 4; ++nj) {
            short8 kf = *(const short8*)(kbase + (size_t)(k0 + nj * 16 + lc) * 64 + 32 + eo);
            s[nj] = __builtin_amdgcn_mfma_f32_16x16x32_bf16(qf1, kf, s[nj], 0, 0, 0);
        }
        if (kb == qb) {
            #pragma unroll
            for (int nj = 0; nj < 4; ++nj)
                #pragma unroll
                for (int r = 0; r < 4; ++r)
                    if (k0 + nj * 16 + lc > r0 + lg * 4 + r) s[nj][r] = -INFINITY;
        }
        #pragma unroll
        for (int r = 0; r < 4; ++r) {
            float ps = 0.f;
            #pragma unroll
            for (int nj = 0; nj < 4; ++nj) {
                float p = __expf(s[nj][r]);   // exp(-inf)=0 above diagonal
                ps += p;
                ldsP[w][lg * 4 + r][nj * 16 + lc] = f2bf(p);
            }
            ps += __shfl_xor(ps, 1);
            ps += __shfl_xor(ps, 2);
            ps += __shfl_xor(ps, 4);
            ps += __shfl_xor(ps, 8);
            lsum[r] += ps;
        }
        #pragma unroll
        for (int ks = 0; ks < 2; ++ks) {
            short8 pa = *(const short8*)&ldsP[w][lc][ks * 32 + lg * 8];
            #pragma unroll
            for (int nj = 0; nj < 4; ++nj) {
                short8 vf = *(const short8*)(vbase + (size_t)(nj * 16 + lc) * SQ + k0 + ks * 32 + eo);
                o[nj] = __builtin_amdgcn_mfma_f32_16x16x32_bf16(pa, vf, o[nj], 0, 0, 0);
            }
        }
    }
    size_t pb = ((size_t)sp * NB + b) * SQ;
    #pragma unroll
    for (int r = 0; r < 4; ++r) {
        int row = r0 + lg * 4 + r;
        if (lc == 0) lpart[pb + row] = lsum[r];
        #pragma unroll
        for (int nj = 0; nj < 4; ++nj)
            op[(pb + row) * 64 + nj * 16 + lc] = o[nj][r];
    }
}

// ---------------- K3: combine partials (plain sums) + fused MLP; 8 rows/block
__global__ __launch_bounds__(256) void k_combine(const float* __restrict__ op,
                                                 const float* __restrict__ lpart,
                                                 const float* __restrict__ W1,
                                                 const float* __restrict__ b1,
                                                 const float* __restrict__ W2,
                                                 const float* __restrict__ b2,
                                                 float* __restrict__ x,
                                                 float* __restrict__ linv) {
    int row0 = blockIdx.x * 8;
    int tid = threadIdx.x, w = tid >> 6, l = tid & 63;
    __shared__ float w1l[64][64];   // 64 lanes stride-1 -> 2-way bank alias (free)
    __shared__ float aol[8][64];
    {   // cooperative W1 stage: 4096 floats = 1024 float4
        const float4* src = (const float4*)W1;
        float4* dst = (float4*)&w1l[0][0];
        #pragma unroll
        for (int i = 0; i < 4; ++i) dst[tid + i * 256] = src[tid + i * 256];
    }
    float inv2[2];
    #pragma unroll
    for (int rr = 0; rr < 2; ++rr) {
        int grow = row0 + w * 2 + rr;
        int b = grow >> 11, s = grow & 2047;
        int nsp = (s >> 6) + 1; if (nsp > NSP) nsp = NSP;
        float od = 0.f, lt = 0.f;
        for (int sp = 0; sp < nsp; ++sp) {
            size_t base = (size_t)(sp * NB + b) * SQ + s;
            od += op[base * 64 + l];
            lt += lpart[base];
        }
        float inv = 1.f / lt;
        inv2[rr] = inv;
        aol[w * 2 + rr][l] = od * inv;   // wave-local write, read by same wave
        if (l == 0) linv[grow] = inv;
    }
    __syncthreads();   // w1l visible to all
    #pragma unroll
    for (int rr = 0; rr < 2; ++rr) {
        int grow = row0 + w * 2 + rr;
        float t = b1[l];
        #pragma unroll 16
        for (int d = 0; d < 64; ++d) t += aol[w * 2 + rr][d] * w1l[d][l];
        float h = fmaxf(t, 0.f);
        float px = h * W2[l];
        px += __shfl_xor(px, 1);
        px += __shfl_xor(px, 2);
        px += __shfl_xor(px, 4);
        px += __shfl_xor(px, 8);
        px += __shfl_xor(px, 16);
        px += __shfl_xor(px, 32);
        if (l == 0) x[grow] = px + b2[0];
    }
    (void)inv2;
}

// ---------------- K4: attn writer — recompute S, write exp(S)*invl; zeros above diag
__global__ __launch_bounds__(256) void k_attnw(const short* __restrict__ qw,
                                               const short* __restrict__ kw,
                                               const float* __restrict__ linv,
                                               float* __restrict__ attn) {
    int kb = blockIdx.x, qb = blockIdx.y, b = blockIdx.z;
    int q0 = qb * 64, k0 = kb * 64;
    float* abase = attn + (size_t)b * SQ * SQ;
    int tid = threadIdx.x;
    if (kb > qb) {   // strictly-upper tile: pure zero-fill, fully coalesced
        int row = q0 + (tid >> 2);
        float4* dst = (float4*)(abase + (size_t)row * SQ + k0 + (tid & 3) * 16);
        float4 z = {0.f, 0.f, 0.f, 0.f};
        dst[0] = z; dst[1] = z; dst[2] = z; dst[3] = z;
        return;
    }
    int w = tid >> 6, l = tid & 63, lg = l >> 4, lc = l & 15;
    int r0 = q0 + w * 16, eo = lg * 8;
    const short* qbase = qw + (size_t)b * SQ * 64;
    const short* kbase = kw + (size_t)b * SQ * 64;
    short8 qf0 = *(const short8*)(qbase + (size_t)(r0 + lc) * 64 + eo);
    short8 qf1 = *(const short8*)(qbase + (size_t)(r0 + lc) * 64 + 32 + eo);
    f32x4 s[4];
    #pragma unroll
    for (int nj = 0; nj < 4; ++nj) s[nj] = (f32x4){0.f, 0.f, 0.f, 0.f};
    #pragma unroll
    for (int nj = 0; nj < 4; ++nj) {
        short8 kf = *(const short8*)(kbase + (size_t)(k0 + nj * 16 + lc) * 64 + eo);
        s[nj] = __builtin_amdgcn_mfma_f32_16x16x32_bf16(qf0, kf, s[nj], 0, 0, 0);
    }
    #pragma unroll
    for (int nj = 0; nj < 4; ++nj) {
        short8 kf = *(const short8*)(kbase + (size_t)(k0 + nj * 16 + lc) * 64 + 32 + eo);
        s[nj] = __builtin_amdgcn_mfma_f32_16x16x32_bf16(qf1, kf, s[nj], 0, 0, 0);
    }
    #pragma unroll
    for (int r = 0; r < 4; ++r) {
        int row = r0 + lg * 4 + r;
        float iv = linv[(size_t)b * SQ + row];
        #pragma unroll
        for (int nj = 0; nj < 4; ++nj) {
            int col = k0 + nj * 16 + lc;
            float p = (col <= row) ? __expf(s[nj][r]) * iv : 0.f;
            abase[(size_t)row * SQ + col] = p;
        }
    }
}

extern "C" void kernel_launch(void* const* d_in, const int* in_sizes, int n_in,
                              void* d_out, int out_size, void* d_ws, size_t ws_size,
                              hipStream_t stream) {
    const float* obs = (const float*)d_in[0];
    const float* Wq  = (const float*)d_in[2];
    const float* Wk  = (const float*)d_in[3];
    const float* Wv  = (const float*)d_in[4];
    const float* W1  = (const float*)d_in[5];
    const float* b1  = (const float*)d_in[6];
    const float* W2  = (const float*)d_in[7];
    const float* b2  = (const float*)d_in[8];

    float* x    = (float*)d_out;                    // [16384]
    float* attn = (float*)d_out + NB * SQ;          // [8][2048][2048]

    // flash o-partials live inside the attn output region (fully overwritten by k_attnw)
    float* op = attn;                               // 8 sp * 16384 rows * 64 f32 = 32 MiB

    char* ws = (char*)d_ws;
    short* wt    = (short*)(ws);                    // 192*256 bf16
    short* qw    = (short*)(ws + 131072);           // 16384*64 bf16
    short* kw    = (short*)(ws + 2228224);          // 16384*64 bf16
    short* vt    = (short*)(ws + 4325376);          // 8*64*2048 bf16
    float* lpart = (float*)(ws + 6422528);          // 8 sp * 16384 f32
    float* linv  = (float*)(ws + 6946816);          // 16384 f32

    k_wt<<<dim3(192), dim3(256), 0, stream>>>(Wq, Wk, Wv, wt);
    k_proj<<<dim3(1024), dim3(256), 0, stream>>>(obs, wt, qw, kw, vt);
    k_flash<<<dim3(32, NSP, NB), dim3(256), 0, stream>>>(qw, kw, vt, op, lpart);
    k_combine<<<dim3(2048), dim3(256), 0, stream>>>(op, lpart, W1, b1, W2, b2, x, linv);
    k_attnw<<<dim3(32, 32, NB), dim3(256), 0, stream>>>(qw, kw, linv, attn);
}

// Round 6
// 140.398 us; speedup vs baseline: 1.2120x; 1.1311x over previous
//
#include <hip/hip_runtime.h>
#include <hip/hip_bf16.h>
#include <math.h>

#define NB 8
#define SQ 2048
#define NSP 4    // kv splits in flash pass

typedef __attribute__((ext_vector_type(8))) short short8;
typedef __attribute__((ext_vector_type(4))) float f32x4;

__device__ __forceinline__ short f2bf(float f) {
    union { float f; unsigned u; } v; v.f = f;
    unsigned r = v.u + 0x7FFF + ((v.u >> 16) & 1);  // RNE
    return (short)(r >> 16);
}

// ---------------- K0: build WT bf16 [192][256]  (rows 0-63 Wq, 64-127 Wk, 128-191 Wv)
__global__ __launch_bounds__(256) void k_wt(const float* __restrict__ Wq,
                                            const float* __restrict__ Wk,
                                            const float* __restrict__ Wv,
                                            short* __restrict__ wt) {
    int o = blockIdx.x * 256 + threadIdx.x;   // < 192*256
    int row = o >> 8, e = o & 255;
    int w = row >> 6, d = row & 63;
    const float* W = (w == 0) ? Wq : ((w == 1) ? Wk : Wv);
    wt[o] = f2bf(W[e * 64 + d]);
}

// ---------------- K1: projection GEMM, 16 rows/block, waves split cols {q,k,v}
__global__ __launch_bounds__(256, 4) void k_proj(const float* __restrict__ obs,
                                                 const short* __restrict__ wt,
                                                 short* __restrict__ qw,
                                                 short* __restrict__ kw,
                                                 short* __restrict__ vt) {
    int tid = threadIdx.x, w = tid >> 6, l = tid & 63, lg = l >> 4, lc = l & 15;
    int r0 = blockIdx.x * 16;
    int arow = r0 + lc;
    f32x4 accq = {0.f,0.f,0.f,0.f}, acck = {0.f,0.f,0.f,0.f}, accv = {0.f,0.f,0.f,0.f};
    const short* wq = wt + (size_t)(w * 16 + lc) * 256;
    const short* wk = wt + (size_t)(64 + w * 16 + lc) * 256;
    const short* wv = wt + (size_t)(128 + w * 16 + lc) * 256;
    #pragma unroll
    for (int ks = 0; ks < 8; ++ks) {
        int e0 = ks * 32 + lg * 8;
        const float* ap = obs + (size_t)arow * 256 + e0;
        float4 f0 = *(const float4*)ap;
        float4 f1 = *(const float4*)(ap + 4);
        short8 a;
        a[0] = f2bf(f0.x); a[1] = f2bf(f0.y); a[2] = f2bf(f0.z); a[3] = f2bf(f0.w);
        a[4] = f2bf(f1.x); a[5] = f2bf(f1.y); a[6] = f2bf(f1.z); a[7] = f2bf(f1.w);
        accq = __builtin_amdgcn_mfma_f32_16x16x32_bf16(a, *(const short8*)(wq + e0), accq, 0, 0, 0);
        acck = __builtin_amdgcn_mfma_f32_16x16x32_bf16(a, *(const short8*)(wk + e0), acck, 0, 0, 0);
        accv = __builtin_amdgcn_mfma_f32_16x16x32_bf16(a, *(const short8*)(wv + e0), accv, 0, 0, 0);
    }
    const float scale = 0.35355339059327373f;  // 64^-0.25
    __shared__ short ldsv[64][18];
    #pragma unroll
    for (int r = 0; r < 4; ++r) {
        int row = r0 + lg * 4 + r;
        qw[(size_t)row * 64 + w * 16 + lc] = f2bf(accq[r] * scale);
        kw[(size_t)row * 64 + w * 16 + lc] = f2bf(acck[r] * scale);
        ldsv[w * 16 + lc][lg * 4 + r] = f2bf(accv[r]);
    }
    __syncthreads();
    int b = r0 >> 11, s0 = r0 & 2047;
    int d = tid >> 2, sc = (tid & 3) * 4;
    short* dst = vt + (size_t)b * 64 * SQ + (size_t)d * SQ + s0 + sc;
    dst[0] = ldsv[d][sc]; dst[1] = ldsv[d][sc + 1];
    dst[2] = ldsv[d][sc + 2]; dst[3] = ldsv[d][sc + 3];
}

// ---------------- K2: flash — p=exp(s) stored UNNORMALIZED f32 into attn; PV partials + l partials
__global__ __launch_bounds__(256) void k_flash(const short* __restrict__ qw,
                                               const short* __restrict__ kw,
                                               const short* __restrict__ vt,
                                               float* __restrict__ op,
                                               float* __restrict__ lpart,
                                               float* __restrict__ attn) {
    int qb = blockIdx.x, sp = blockIdx.y, b = blockIdx.z;
    if (sp > qb) return;
    int q0 = qb * 64;
    int tid = threadIdx.x, w = tid >> 6, l = tid & 63, lg = l >> 4, lc = l & 15;
    int r0 = q0 + w * 16;
    int eo = lg * 8;
    __shared__ short ldsP[4][16][72];
    const short* qbase = qw + (size_t)b * SQ * 64;
    const short* kbase = kw + (size_t)b * SQ * 64;
    const short* vbase = vt + (size_t)b * 64 * SQ;
    float* abase = attn + (size_t)b * SQ * SQ;
    short8 qf0 = *(const short8*)(qbase + (size_t)(r0 + lc) * 64 + eo);
    short8 qf1 = *(const short8*)(qbase + (size_t)(r0 + lc) * 64 + 32 + eo);
    float lsum[4];
    f32x4 o[4];
    #pragma unroll
    for (int r = 0; r < 4; ++r) lsum[r] = 0.f;
    #pragma unroll
    for (int nj = 0; nj < 4; ++nj) o[nj] = (f32x4){0.f, 0.f, 0.f, 0.f};

    for (int kb = sp; kb <= qb; kb += NSP) {
        int k0 = kb * 64;
        f32x4 s[4];
        #pragma unroll
        for (int nj = 0; nj < 4; ++nj) s[nj] = (f32x4){0.f, 0.f, 0.f, 0.f};
        #pragma unroll
        for (int nj = 0; nj < 4; ++nj) {
            short8 kf = *(const short8*)(kbase + (size_t)(k0 + nj * 16 + lc) * 64 + eo);
            s[nj] = __builtin_amdgcn_mfma_f32_16x16x32_bf16(qf0, kf, s[nj], 0, 0, 0);
        }
        #pragma unroll
        for (int nj = 0; nj < 4; ++nj) {
            short8 kf = *(const short8*)(kbase + (size_t)(k0 + nj * 16 + lc) * 64 + 32 + eo);
            s[nj] = __builtin_amdgcn_mfma_f32_16x16x32_bf16(qf1, kf, s[nj], 0, 0, 0);
        }
        if (kb == qb) {
            #pragma unroll
            for (int nj = 0; nj < 4; ++nj)
                #pragma unroll
                for (int r = 0; r < 4; ++r)
                    if (k0 + nj * 16 + lc > r0 + lg * 4 + r) s[nj][r] = -INFINITY;
        }
        #pragma unroll
        for (int r = 0; r < 4; ++r) {
            int row = r0 + lg * 4 + r;
            float ps = 0.f;
            #pragma unroll
            for (int nj = 0; nj < 4; ++nj) {
                float p = __expf(s[nj][r]);   // exp(-inf)=0 above diagonal
                ps += p;
                ldsP[w][lg * 4 + r][nj * 16 + lc] = f2bf(p);
                abase[(size_t)row * SQ + k0 + nj * 16 + lc] = p;  // unnormalized, scaled later
            }
            ps += __shfl_xor(ps, 1);
            ps += __shfl_xor(ps, 2);
            ps += __shfl_xor(ps, 4);
            ps += __shfl_xor(ps, 8);
            lsum[r] += ps;
        }
        #pragma unroll
        for (int ks = 0; ks < 2; ++ks) {
            short8 pa = *(const short8*)&ldsP[w][lc][ks * 32 + lg * 8];
            #pragma unroll
            for (int nj = 0; nj < 4; ++nj) {
                short8 vf = *(const short8*)(vbase + (size_t)(nj * 16 + lc) * SQ + k0 + ks * 32 + eo);
                o[nj] = __builtin_amdgcn_mfma_f32_16x16x32_bf16(pa, vf, o[nj], 0, 0, 0);
            }
        }
    }
    size_t pb = ((size_t)sp * NB + b) * SQ;
    #pragma unroll
    for (int r = 0; r < 4; ++r) {
        int row = r0 + lg * 4 + r;
        if (lc == 0) lpart[pb + row] = lsum[r];
        #pragma unroll
        for (int nj = 0; nj < 4; ++nj)
            op[(pb + row) * 64 + nj * 16 + lc] = o[nj][r];
    }
}

// ---------------- K3: reduce l partials -> 1/l
__global__ __launch_bounds__(256) void k_lred(const float* __restrict__ lpart,
                                              float* __restrict__ linv) {
    int g = blockIdx.x * 256 + threadIdx.x;   // < 16384
    int s = g & 2047, b = g >> 11;
    int nsp = (s >> 6) + 1; if (nsp > NSP) nsp = NSP;
    float t = 0.f;
    for (int sp = 0; sp < nsp; ++sp) t += lpart[((size_t)sp * NB + b) * SQ + s];
    linv[g] = 1.f / t;
}

// ---------------- K4: combine PV partials + fused MLP -> x
__global__ __launch_bounds__(256) void k_combine(const float* __restrict__ op,
                                                 const float* __restrict__ linv,
                                                 const float* __restrict__ W1,
                                                 const float* __restrict__ b1,
                                                 const float* __restrict__ W2,
                                                 const float* __restrict__ b2,
                                                 float* __restrict__ x) {
    int row0 = blockIdx.x * 8;
    int tid = threadIdx.x, w = tid >> 6, l = tid & 63;
    __shared__ float w1l[64][64];
    __shared__ float aol[8][64];
    {   // cooperative W1 stage: 4096 floats = 1024 float4
        const float4* src = (const float4*)W1;
        float4* dst = (float4*)&w1l[0][0];
        #pragma unroll
        for (int i = 0; i < 4; ++i) dst[tid + i * 256] = src[tid + i * 256];
    }
    #pragma unroll
    for (int rr = 0; rr < 2; ++rr) {
        int grow = row0 + w * 2 + rr;
        int b = grow >> 11, s = grow & 2047;
        int nsp = (s >> 6) + 1; if (nsp > NSP) nsp = NSP;
        float od = 0.f;
        for (int sp = 0; sp < nsp; ++sp)
            od += op[(((size_t)sp * NB + b) * SQ + s) * 64 + l];
        aol[w * 2 + rr][l] = od * linv[grow];   // wave-local write/read
    }
    __syncthreads();
    #pragma unroll
    for (int rr = 0; rr < 2; ++rr) {
        int grow = row0 + w * 2 + rr;
        float t = b1[l];
        #pragma unroll 16
        for (int d = 0; d < 64; ++d) t += aol[w * 2 + rr][d] * w1l[d][l];
        float h = fmaxf(t, 0.f);
        float px = h * W2[l];
        px += __shfl_xor(px, 1);
        px += __shfl_xor(px, 2);
        px += __shfl_xor(px, 4);
        px += __shfl_xor(px, 8);
        px += __shfl_xor(px, 16);
        px += __shfl_xor(px, 32);
        if (l == 0) x[grow] = px + b2[0];
    }
}

// ---------------- K5: streaming in-place scale + zero-fill; 1 KB contiguous per wave-inst
__global__ __launch_bounds__(256) void k_scale(const float* __restrict__ linv,
                                               float* __restrict__ attn) {
    int csp = blockIdx.x, qb = blockIdx.y, b = blockIdx.z;
    int tid = threadIdx.x, w = tid >> 6, l = tid & 63;
    float* abase = attn + (size_t)b * SQ * SQ;
    int colb = csp * 256 + l * 4;
    if (csp * 4 > qb) {   // chunk entirely above all written tiles: pure zero-fill
        float4 z = {0.f, 0.f, 0.f, 0.f};
        #pragma unroll
        for (int r = 0; r < 16; ++r) {
            int row = qb * 64 + w * 16 + r;
            *(float4*)(abase + (size_t)row * SQ + colb) = z;
        }
        return;
    }
    #pragma unroll
    for (int r = 0; r < 16; ++r) {
        int row = qb * 64 + w * 16 + r;
        float inv = linv[(size_t)b * SQ + row];
        int lim = row | 63;   // flash wrote cols [0, lim]; beyond is garbage -> 0
        float* p = abase + (size_t)row * SQ + colb;
        float4 v = *(const float4*)p;
        float4 o;
        o.x = (colb + 0 <= lim) ? v.x * inv : 0.f;
        o.y = (colb + 1 <= lim) ? v.y * inv : 0.f;
        o.z = (colb + 2 <= lim) ? v.z * inv : 0.f;
        o.w = (colb + 3 <= lim) ? v.w * inv : 0.f;
        *(float4*)p = o;
    }
}

extern "C" void kernel_launch(void* const* d_in, const int* in_sizes, int n_in,
                              void* d_out, int out_size, void* d_ws, size_t ws_size,
                              hipStream_t stream) {
    const float* obs = (const float*)d_in[0];
    const float* Wq  = (const float*)d_in[2];
    const float* Wk  = (const float*)d_in[3];
    const float* Wv  = (const float*)d_in[4];
    const float* W1  = (const float*)d_in[5];
    const float* b1  = (const float*)d_in[6];
    const float* W2  = (const float*)d_in[7];
    const float* b2  = (const float*)d_in[8];

    float* x    = (float*)d_out;                    // [16384]
    float* attn = (float*)d_out + NB * SQ;          // [8][2048][2048]

    char* ws = (char*)d_ws;
    short* wt    = (short*)(ws);                    // 192*256 bf16
    short* qw    = (short*)(ws + 131072);           // 16384*64 bf16
    short* kw    = (short*)(ws + 2228224);          // 16384*64 bf16
    short* vt    = (short*)(ws + 4325376);          // 8*64*2048 bf16
    float* lpart = (float*)(ws + 6422528);          // 4 sp * 16384 f32
    float* linv  = (float*)(ws + 6684672);          // 16384 f32
    float* op    = (float*)(ws + 6750208);          // 4 sp * 16384 * 64 f32 = 16 MiB

    k_wt<<<dim3(192), dim3(256), 0, stream>>>(Wq, Wk, Wv, wt);
    k_proj<<<dim3(1024), dim3(256), 0, stream>>>(obs, wt, qw, kw, vt);
    k_flash<<<dim3(32, NSP, NB), dim3(256), 0, stream>>>(qw, kw, vt, op, lpart, attn);
    k_lred<<<dim3(64), dim3(256), 0, stream>>>(lpart, linv);
    k_combine<<<dim3(2048), dim3(256), 0, stream>>>(op, linv, W1, b1, W2, b2, x);
    k_scale<<<dim3(8, 32, NB), dim3(256), 0, stream>>>(linv, attn);
}